// Round 14
// baseline (282.240 us; speedup 1.0000x reference)
//
#include <hip/hip_runtime.h>

typedef unsigned short u16;
typedef unsigned int u32;
typedef unsigned long long u64;
typedef __bf16 bf16_t;
typedef __bf16 bf16x8 __attribute__((ext_vector_type(8)));
typedef float f32x4 __attribute__((ext_vector_type(4)));
typedef u32 u32x4 __attribute__((ext_vector_type(4)));   // native vector: OK for NT builtins

#define NN 5000
#define NF 512
#define NH 64
#define HEADS 8
#define NCLS 40
#define CAP 128
#define LRELU 0.2f
#define BMW 80                       // bitmask u64 words per row

#define CVT_BIG 320
#define BM_BLKS 1250                 // 4 waves/block, wave per row
#define CVT_GRID (CVT_BIG + 8 + BM_BLKS)

// ---- dtype probe: adj[0][0]==1.0 always (self-loop). fp32 word0=0x3F800000 (low16==0);
// ---- packed-bf16 word0 low half = 0x3F80 != 0. (R2-R13: fp32 path taken on this harness.)
__device__ __forceinline__ bool adj_is_bf16(const void* adj) {
    return ((*(const u32*)adj) & 0xFFFFu) != 0u;
}
__device__ __forceinline__ u16 rne_bf16(float f) {
    u32 u = __float_as_uint(f);
    u += 0x7FFFu + ((u >> 16) & 1u);
    return (u16)(u >> 16);
}
__device__ __forceinline__ float up_bf16(u16 h) {
    return __uint_as_float((u32)h << 16);
}
__device__ __forceinline__ u32x4 ntload4(const void* p, int idx) {
    return __builtin_nontemporal_load(((const u32x4*)p) + idx);
}

// ---------------- K0 cvt: canonicalize inputs + adjacency -> bitmask ----------------
__global__ __launch_bounds__(256) void cvt(const void* __restrict__ x, const void* __restrict__ W_h,
                                           const void* __restrict__ adj,
                                           const void* a_h, const void* W_o, const void* a_o,
                                           const void* f1w, const void* f1b,
                                           const void* f2w, const void* f2b,
                                           u16* __restrict__ xc, u16* __restrict__ whc,
                                           float* a_hc, float* W_oc, float* a_oc,
                                           float* f1wc, float* f1bc, float* f2wc, float* f2bc,
                                           u64* __restrict__ bm) {
    const bool isb = adj_is_bf16(adj);
    const int b = blockIdx.x;
    if (b < CVT_BIG) {
        const int X4 = NN * NF / 4;                          // 640,000
        const int T4 = X4 + HEADS * NF * NH / 4;             // 705,536
        for (int i = b * 256 + threadIdx.x; i < T4; i += CVT_BIG * 256) {
            const void* src; u16* dst; int off;
            if (i < X4) { src = x; dst = xc; off = i; }
            else        { src = W_h; dst = whc; off = i - X4; }
            ushort4 o;
            if (isb) {
                o = ((const ushort4*)src)[off];              // already bf16: copy 8 B
            } else {
                u32x4 vv = ntload4(src, off);
                o.x = rne_bf16(__uint_as_float(vv[0])); o.y = rne_bf16(__uint_as_float(vv[1]));
                o.z = rne_bf16(__uint_as_float(vv[2])); o.w = rne_bf16(__uint_as_float(vv[3]));
            }
            ((ushort4*)dst)[off] = o;
        }
    } else if (b < CVT_BIG + 8) {
        const int s0 = HEADS * 2 * NH, s1 = HEADS * NH * NH, s2 = 2 * NH,
                  s3 = NH * 200, s4 = 200, s5 = 200 * NCLS, s6 = NCLS;
        const int total = s0 + s1 + s2 + s3 + s4 + s5 + s6;  // 54,960
        for (int i = (b - CVT_BIG) * 256 + threadIdx.x; i < total; i += 8 * 256) {
            const void* src; float* dst; int off = i;
            if (off < s0) { src = a_h; dst = a_hc; }
            else if ((off -= s0) < s1) { src = W_o;  dst = W_oc; }
            else if ((off -= s1) < s2) { src = a_o;  dst = a_oc; }
            else if ((off -= s2) < s3) { src = f1w;  dst = f1wc; }
            else if ((off -= s3) < s4) { src = f1b;  dst = f1bc; }
            else if ((off -= s4) < s5) { src = f2w;  dst = f2wc; }
            else { off -= s5;           src = f2b;  dst = f2bc; }
            dst[off] = isb ? up_bf16(((const u16*)src)[off]) : ((const float*)src)[off];
        }
    } else {
        // ---- adjacency -> bitmask: wave per row, NT streaming reads ----
        const int lane = threadIdx.x & 63;
        const int wid  = threadIdx.x >> 6;
        const int r = (b - CVT_BIG - 8) * 4 + wid;           // exact 5000
        u64* bmrow = bm + (size_t)r * BMW;
        if (!isb) {
            const float* row = (const float*)adj + (size_t)r * NN;     // 1250 u32x4 chunks
            #pragma unroll
            for (int pass = 0; pass < 2; ++pass) {
                u32x4 v[10];
                #pragma unroll
                for (int k = 0; k < 10; ++k) {
                    int c = (pass * 10 + k) * 64 + lane;
                    v[k] = (c < 1250) ? ntload4(row, c) : (u32x4){0u, 0u, 0u, 0u};
                }
                #pragma unroll
                for (int k = 0; k < 10; ++k) {
                    int i = pass * 10 + k;
                    #pragma unroll
                    for (int j = 0; j < 4; ++j) {
                        u64 m = __ballot(v[k][j] != 0u);
                        if (lane == j) bmrow[i * 4 + j] = m;
                    }
                }
            }
        } else {
            const u16* row = (const u16*)adj + (size_t)r * NN;         // 625 u32x4 chunks
            u32x4 v[10];
            #pragma unroll
            for (int k = 0; k < 10; ++k) {
                int c = k * 64 + lane;
                v[k] = (c < 625) ? ntload4(row, c) : (u32x4){0u, 0u, 0u, 0u};
            }
            #pragma unroll
            for (int k = 0; k < 10; ++k) {
                #pragma unroll
                for (int j = 0; j < 4; ++j) {
                    u64 mlo = __ballot((v[k][j] & 0xFFFFu) != 0u);
                    u64 mhi = __ballot((v[k][j] >> 16) != 0u);
                    if (lane == 2 * j)     bmrow[k * 8 + 2 * j]     = mlo;
                    if (lane == 2 * j + 1) bmrow[k * 8 + 2 * j + 1] = mhi;
                }
            }
        }
    }
}

// ---------------- K1: Wh = x @ W_h (bf16 MFMA) + fused f1/f2 epilogue ----------------
// C/D mapping row=(lane>>4)*4+r, col=lane&15 (R3 runtime probe: flag=1).
// Wh stored NODE-MAJOR [n][h*64+o] (R10).
__global__ __launch_bounds__(256) void gemm1_f(const bf16_t* __restrict__ x,
                                               const bf16_t* __restrict__ W_h,
                                               const float* __restrict__ a_h,
                                               float* __restrict__ Wh,
                                               float* __restrict__ f1,
                                               float* __restrict__ f2) {
    const int lane = threadIdx.x & 63;
    const int wid  = threadIdx.x >> 6;    // 16-col tile
    const int rg = blockIdx.x;            // 0..78 (79*64 = 5056 rows, guarded)
    const int h  = blockIdx.y;
    const int quad = lane >> 4;
    const int lr   = lane & 15;
    const int kq   = quad * 8;
    const int nCol = wid * 16 + lr;
    const bf16_t* Bh = W_h + (size_t)h * NF * NH;
    __shared__ float f1s[4][64], f2s[4][64];

    bf16x8 bfrag[16];
    #pragma unroll
    for (int s = 0; s < 16; ++s) {
        bf16x8 bb;
        #pragma unroll
        for (int j = 0; j < 8; ++j) bb[j] = Bh[(s * 32 + kq + j) * NH + nCol];
        bfrag[s] = bb;
    }
    const float a1c = a_h[h * 128 + nCol];
    const float a2c = a_h[h * 128 + NH + nCol];

    for (int t = 0; t < 4; ++t) {
        const int rb = rg * 64 + t * 16;
        int row  = rb + lr;
        int rowc = row < NN ? row : NN - 1;
        const bf16_t* xp = x + (size_t)rowc * NF + kq;
        f32x4 acc = {0.f, 0.f, 0.f, 0.f};
        #pragma unroll
        for (int s = 0; s < 16; ++s) {
            bf16x8 a = *(const bf16x8*)(xp + s * 32);
            acc = __builtin_amdgcn_mfma_f32_16x16x32_bf16(a, bfrag[s], acc, 0, 0, 0);
        }
        #pragma unroll
        for (int r = 0; r < 4; ++r) {
            int gr = rb + quad * 4 + r;
            if (gr < NN) Wh[(size_t)gr * (HEADS * NH) + h * NH + nCol] = acc[r];  // node-major
            float p1 = acc[r] * a1c, p2 = acc[r] * a2c;
            #pragma unroll
            for (int o = 8; o; o >>= 1) { p1 += __shfl_xor(p1, o); p2 += __shfl_xor(p2, o); }
            if (lr == 0) { f1s[wid][t * 16 + quad * 4 + r] = p1; f2s[wid][t * 16 + quad * 4 + r] = p2; }
        }
    }
    __syncthreads();
    if (wid == 0) {
        int gr = rg * 64 + lane;
        if (gr < NN) {
            f1[h * NN + gr] = f1s[0][lane] + f1s[1][lane] + f1s[2][lane] + f1s[3][lane];
            f2[h * NN + gr] = f2s[0][lane] + f2s[1][lane] + f2s[2][lane] + f2s[3][lane];
        }
    }
}

// ---------------- K2 agg1g: bitmask decode + layer-1 attention + FUSED gemm2 ----------------
// h1 lives only in LDS (never global). Epilogue: Wh2[n] = h1[n] @ W_o + g1/g2, same
// summation order as R13's gemm2_4 (4x128 k-slices ascending) -> bit-identical output.
__global__ __launch_bounds__(256) void agg1g(const void* __restrict__ adj,
                                             const u64* __restrict__ bm,
                                             const float* __restrict__ Wh,
                                             const float* __restrict__ f1,
                                             const float* __restrict__ f2,
                                             const float* __restrict__ W_o,
                                             const float* __restrict__ a_o,
                                             int* __restrict__ nbr, int* __restrict__ deg,
                                             float* __restrict__ Wh2,
                                             float* __restrict__ g1, float* __restrict__ g2) {
    const bool isb = adj_is_bf16(adj);
    const int lane = threadIdx.x & 63;
    const int wid  = threadIdx.x >> 6;
    const int t = threadIdx.x;
    const int n = blockIdx.x;               // 5000 blocks
    __shared__ int   s_nbr[CAP];
    __shared__ int   s_dall;
    __shared__ float s_h1[HEADS * NH];      // node n's concat features (LDS only)
    __shared__ float s_ps[4][NH];

    if (wid == 0) {
        const u64* bmrow = bm + (size_t)n * BMW;
        int base = 0;
        #pragma unroll
        for (int r2 = 0; r2 < 2; ++r2) {
            int w = r2 * 64 + lane;
            u64 mw = (w < BMW) ? bmrow[w] : 0ull;
            int pc = __popcll(mw);
            int scan = pc;
            #pragma unroll
            for (int o = 1; o < 64; o <<= 1) {
                int tt = __shfl_up(scan, o);
                if (lane >= o) scan += tt;
            }
            int off = base + scan - pc;     // exclusive prefix
            while (mw) {
                int bb = __ffsll(mw) - 1;
                mw &= mw - 1;
                int elem;
                if (!isb) elem = ((w >> 2) * 64 + bb) * 4 + (w & 3);
                else      elem = ((w >> 3) * 64 + bb) * 8 + (w & 7);
                if (off < CAP) s_nbr[off] = elem;
                ++off;
            }
            base += __shfl(scan, 63);
        }
        if (lane == 0) s_dall = base < CAP ? base : CAP;
    }
    __syncthreads();
    const int dall = s_dall;
    for (int i = t; i < dall; i += 256) nbr[(size_t)n * CAP + i] = s_nbr[i];
    if (t == 0) deg[n] = dall;

    // ---- both heads (ha=wid, hb=wid+4) in registers; no LDS in hot loop ----
    const int ha = wid, hb = wid + 4;
    const int nb0 = (lane < dall) ? s_nbr[lane] : 0;
    const int nb1 = (lane + 64 < dall) ? s_nbr[lane + 64] : 0;
    const float f10 = f1[ha * NN + n], f11 = f1[hb * NN + n];
    const float* f2ha = f2 + (size_t)ha * NN;
    const float* f2hb = f2 + (size_t)hb * NN;

    float e00 = -INFINITY, e01 = -INFINITY, e10 = -INFINITY, e11 = -INFINITY;
    if (lane < dall) {
        float a = f10 + f2ha[nb0]; e00 = a > 0.f ? a : LRELU * a;
        float b = f11 + f2hb[nb0]; e10 = b > 0.f ? b : LRELU * b;
    }
    if (lane + 64 < dall) {
        float a = f10 + f2ha[nb1]; e01 = a > 0.f ? a : LRELU * a;
        float b = f11 + f2hb[nb1]; e11 = b > 0.f ? b : LRELU * b;
    }
    float mx0 = fmaxf(e00, e01), mx1 = fmaxf(e10, e11);
    #pragma unroll
    for (int o = 32; o; o >>= 1) {
        mx0 = fmaxf(mx0, __shfl_xor(mx0, o));
        mx1 = fmaxf(mx1, __shfl_xor(mx1, o));
    }
    float p00 = lane < dall ? expf(e00 - mx0) : 0.f;
    float p01 = lane + 64 < dall ? expf(e01 - mx0) : 0.f;
    float p10 = lane < dall ? expf(e10 - mx1) : 0.f;
    float p11 = lane + 64 < dall ? expf(e11 - mx1) : 0.f;
    float sm0 = p00 + p01, sm1 = p10 + p11;
    #pragma unroll
    for (int o = 32; o; o >>= 1) { sm0 += __shfl_xor(sm0, o); sm1 += __shfl_xor(sm1, o); }

    float A0 = 0.f, A1 = 0.f, A2 = 0.f, A3 = 0.f;
    float B0 = 0.f, B1 = 0.f, B2 = 0.f, B3 = 0.f;
    const float* W0 = Wh + ha * NH + lane;
    const float* W1 = Wh + hb * NH + lane;
    int j = 0;
    for (; j + 4 <= dall; j += 4) {
        #pragma unroll
        for (int i = 0; i < 4; ++i) {
            int jj = j + i;
            int sl = jj & 63;
            bool lo = jj < 64;                              // wave-uniform
            int   m  = lo ? __shfl(nb0, sl) : __shfl(nb1, sl);
            float a0 = lo ? __shfl(p00, sl) : __shfl(p01, sl);
            float a1 = lo ? __shfl(p10, sl) : __shfl(p11, sl);
            size_t base = (size_t)m * (HEADS * NH);
            float w0 = W0[base], w1 = W1[base];
            if (i == 0) { A0 += a0 * w0; B0 += a1 * w1; }
            else if (i == 1) { A1 += a0 * w0; B1 += a1 * w1; }
            else if (i == 2) { A2 += a0 * w0; B2 += a1 * w1; }
            else { A3 += a0 * w0; B3 += a1 * w1; }
        }
    }
    for (; j < dall; ++j) {
        int sl = j & 63;
        bool lo = j < 64;
        int   m  = lo ? __shfl(nb0, sl) : __shfl(nb1, sl);
        float a0 = lo ? __shfl(p00, sl) : __shfl(p01, sl);
        float a1 = lo ? __shfl(p10, sl) : __shfl(p11, sl);
        size_t base = (size_t)m * (HEADS * NH);
        A0 += a0 * W0[base]; B0 += a1 * W1[base];
    }
    float hv0 = (A0 + A1 + A2 + A3) / sm0;
    float hv1 = (B0 + B1 + B2 + B3) / sm1;
    hv0 = hv0 > 0.f ? hv0 : expf(hv0) - 1.f;                // ELU
    hv1 = hv1 > 0.f ? hv1 : expf(hv1) - 1.f;
    s_h1[ha * NH + lane] = hv0;                             // concat heads (LDS only)
    s_h1[hb * NH + lane] = hv1;
    __syncthreads();

    // ---- fused gemm2: Wh2[n] = s_h1 @ W_o; thread (part=t>>6, o=t&63) ----
    const int o = t & 63, part = t >> 6;
    float acc = 0.f;
    const float* wo = W_o + part * 128 * 64 + o;
    const float* sp = s_h1 + part * 128;
    #pragma unroll 4
    for (int f = 0; f < 128; ++f) acc += sp[f] * wo[f * 64];
    s_ps[part][o] = acc;
    __syncthreads();
    if (t < 64) {
        float w2 = s_ps[0][t] + s_ps[1][t] + s_ps[2][t] + s_ps[3][t];
        Wh2[(size_t)n * NH + t] = w2;
        float p1 = w2 * a_o[t], p2 = w2 * a_o[NH + t];
        #pragma unroll
        for (int s = 32; s; s >>= 1) { p1 += __shfl_xor(p1, s); p2 += __shfl_xor(p2, s); }
        if (t == 0) { g1[n] = p1; g2[n] = p2; }
    }
}

// ---------------- K3: layer-2 attention + aggregation + MLP head ----------------
__global__ __launch_bounds__(256) void agg2_mlp(const float* __restrict__ Wh2,
                                                const float* __restrict__ g1,
                                                const float* __restrict__ g2,
                                                const int* __restrict__ nbr,
                                                const int* __restrict__ deg,
                                                const float* __restrict__ fc1_w,
                                                const float* __restrict__ fc1_b,
                                                const float* __restrict__ fc2_w,
                                                const float* __restrict__ fc2_b,
                                                float* __restrict__ out) {
    const int lane = threadIdx.x & 63;
    const int wid  = threadIdx.x >> 6;
    const int t = threadIdx.x;
    const int n0 = blockIdx.x * 4;          // exact 5000
    const int n = n0 + wid;                 // gather phase: wave = node
    __shared__ float s_alpha[4][CAP];
    __shared__ int   s_nbr[4][CAP];
    __shared__ float s_h2[4][NH];
    __shared__ float s_h3[4][200];
    __shared__ float ps2[2][4][NCLS];
    const int d = deg[n];
    const int* nb = nbr + (size_t)n * CAP;
    const float gn = g1[n];

    float mx = -INFINITY;
    for (int j = lane; j < d; j += 64) {
        int m = nb[j];
        s_nbr[wid][j] = m;
        float e = gn + g2[m];
        e = e > 0.f ? e : LRELU * e;
        s_alpha[wid][j] = e;
        mx = fmaxf(mx, e);
    }
    #pragma unroll
    for (int o = 32; o; o >>= 1) mx = fmaxf(mx, __shfl_xor(mx, o));
    float sm = 0.f;
    for (int j = lane; j < d; j += 64) {
        float p = expf(s_alpha[wid][j] - mx);
        s_alpha[wid][j] = p;
        sm += p;
    }
    #pragma unroll
    for (int o = 32; o; o >>= 1) sm += __shfl_xor(sm, o);

    float acc0 = 0.f, acc1 = 0.f, acc2 = 0.f, acc3 = 0.f;
    int j = 0;
    for (; j + 4 <= d; j += 4) {
        acc0 += s_alpha[wid][j]     * Wh2[(size_t)s_nbr[wid][j]     * NH + lane];
        acc1 += s_alpha[wid][j + 1] * Wh2[(size_t)s_nbr[wid][j + 1] * NH + lane];
        acc2 += s_alpha[wid][j + 2] * Wh2[(size_t)s_nbr[wid][j + 2] * NH + lane];
        acc3 += s_alpha[wid][j + 3] * Wh2[(size_t)s_nbr[wid][j + 3] * NH + lane];
    }
    for (; j < d; ++j) acc0 += s_alpha[wid][j] * Wh2[(size_t)s_nbr[wid][j] * NH + lane];
    s_h2[wid][lane] = (acc0 + acc1 + acc2 + acc3) / sm;
    __syncthreads();

    // fc1: 200 threads x 4 nodes, fc1_w read once/block
    if (t < 200) {
        float b0 = 0.f, b1 = 0.f, b2 = 0.f, b3 = 0.f;
        #pragma unroll 4
        for (int f = 0; f < NH; ++f) {
            float w = fc1_w[f * 200 + t];
            b0 += s_h2[0][f] * w; b1 += s_h2[1][f] * w; b2 += s_h2[2][f] * w; b3 += s_h2[3][f] * w;
        }
        float bb = fc1_b[t];
        b0 += bb; b1 += bb; b2 += bb; b3 += bb;
        s_h3[0][t] = b0 > 0.f ? b0 : expf(b0) - 1.f;
        s_h3[1][t] = b1 > 0.f ? b1 : expf(b1) - 1.f;
        s_h3[2][t] = b2 > 0.f ? b2 : expf(b2) - 1.f;
        s_h3[3][t] = b3 > 0.f ? b3 : expf(b3) - 1.f;
    }
    __syncthreads();

    // fc2: 80 threads = (f-half, class) x 4 nodes; fc2_w read 2x/block
    if (t < 80) {
        const int o = t % 40, fh = t / 40;
        float c0 = 0.f, c1 = 0.f, c2 = 0.f, c3 = 0.f;
        #pragma unroll 4
        for (int f = fh * 100; f < fh * 100 + 100; ++f) {
            float w = fc2_w[f * NCLS + o];
            c0 += s_h3[0][f] * w; c1 += s_h3[1][f] * w; c2 += s_h3[2][f] * w; c3 += s_h3[3][f] * w;
        }
        ps2[fh][0][o] = c0; ps2[fh][1][o] = c1; ps2[fh][2][o] = c2; ps2[fh][3][o] = c3;
    }
    __syncthreads();
    if (t < 160) {
        const int nd = t / 40, o = t % 40;
        out[(size_t)(n0 + nd) * NCLS + o] = ps2[0][nd][o] + ps2[1][nd][o] + fc2_b[o];
    }
}

extern "C" void kernel_launch(void* const* d_in, const int* in_sizes, int n_in,
                              void* d_out, int out_size, void* d_ws, size_t ws_size,
                              hipStream_t stream) {
    const void* x     = d_in[0];
    const void* adj   = d_in[1];
    const void* W_h   = d_in[2];
    const void* a_h   = d_in[3];
    const void* W_o   = d_in[4];
    const void* a_o   = d_in[5];
    const void* fc1_w = d_in[6];
    const void* fc1_b = d_in[7];
    const void* fc2_w = d_in[8];
    const void* fc2_b = d_in[9];
    float* out = (float*)d_out;

    char* ws = (char*)d_ws;                         // all offsets 16B-aligned
    int*   nbr   = (int*)(ws + 0);                  //  2,560,000 B
    int*   deg   = (int*)(ws + 2560000);            //     20,000 B
    float* Wh    = (float*)(ws + 2580000);          // 10,240,000 B (node-major [n][512])
    float* f1    = (float*)(ws + 12820000);         //    160,000 B
    float* f2    = (float*)(ws + 12980000);         //    160,000 B
    float* Wh2   = (float*)(ws + 13140000);         //  1,280,000 B
    float* g1    = (float*)(ws + 14420000);         //     20,000 B
    float* g2    = (float*)(ws + 14440000);         //     20,000 B
    u16*   xc    = (u16*)(ws + 14460000);           //  5,120,000 B
    u16*   whc   = (u16*)(ws + 19580000);           //    524,288 B
    float* a_hc  = (float*)(ws + 20104288);         //      4,096 B
    float* W_oc  = (float*)(ws + 20108384);         //    131,072 B
    float* a_oc  = (float*)(ws + 20239456);         //        512 B
    float* f1wc  = (float*)(ws + 20239968);         //     51,200 B
    float* f1bc  = (float*)(ws + 20291168);         //        800 B
    float* f2wc  = (float*)(ws + 20291968);         //     32,000 B
    float* f2bc  = (float*)(ws + 20323968);         //        160 B
    u64*   bm    = (u64*)(ws + 20324128);           //  3,200,000 B  (total ~23.5 MB)

    cvt<<<CVT_GRID, 256, 0, stream>>>(x, W_h, adj, a_h, W_o, a_o,
                                      fc1_w, fc1_b, fc2_w, fc2_b,
                                      xc, whc, a_hc, W_oc, a_oc,
                                      f1wc, f1bc, f2wc, f2bc, bm);
    gemm1_f<<<dim3(79, HEADS), 256, 0, stream>>>((const bf16_t*)xc, (const bf16_t*)whc,
                                                 a_hc, Wh, f1, f2);
    agg1g<<<NN, 256, 0, stream>>>(adj, bm, Wh, f1, f2, W_oc, a_oc,
                                  nbr, deg, Wh2, g1, g2);
    agg2_mlp<<<NN / 4, 256, 0, stream>>>(Wh2, g1, g2, nbr, deg,
                                         f1wc, f1bc, f2wc, f2bc, out);
}

// Round 15
// 276.999 us; speedup vs baseline: 1.0189x; 1.0189x over previous
//
#include <hip/hip_runtime.h>

typedef unsigned short u16;
typedef unsigned int u32;
typedef unsigned long long u64;
typedef __bf16 bf16_t;
typedef __bf16 bf16x8 __attribute__((ext_vector_type(8)));
typedef float f32x4 __attribute__((ext_vector_type(4)));
typedef u32 u32x4 __attribute__((ext_vector_type(4)));   // native vector: OK for NT builtins

#define NN 5000
#define NF 512
#define NH 64
#define HEADS 8
#define NCLS 40
#define CAP 128
#define LRELU 0.2f
#define BMW 80                       // bitmask u64 words per row

#define CVT_BIG 320
#define BM_BLKS 1250                 // 4 waves/block, wave per row
#define CVT_GRID (CVT_BIG + 8 + BM_BLKS)

// ---- dtype probe: adj[0][0]==1.0 always (self-loop). fp32 word0=0x3F800000 (low16==0);
// ---- packed-bf16 word0 low half = 0x3F80 != 0. (R2-R14: fp32 path taken on this harness.)
__device__ __forceinline__ bool adj_is_bf16(const void* adj) {
    return ((*(const u32*)adj) & 0xFFFFu) != 0u;
}
__device__ __forceinline__ u16 rne_bf16(float f) {
    u32 u = __float_as_uint(f);
    u += 0x7FFFu + ((u >> 16) & 1u);
    return (u16)(u >> 16);
}
__device__ __forceinline__ float up_bf16(u16 h) {
    return __uint_as_float((u32)h << 16);
}
__device__ __forceinline__ u32x4 ntload4(const void* p, int idx) {
    return __builtin_nontemporal_load(((const u32x4*)p) + idx);
}

// ---------------- K0 cvt: canonicalize inputs + adjacency -> bitmask ----------------
// Bitmask layout (row stride BMW u64): fp32: word w=(i*4+j), bit b -> elem (i*64+b)*4+j.
// bf16: word w=(i*8+t), bit b -> elem (i*64+b)*8+t. Order-permuted is fine (softmax is
// order-invariant); decoder (agg1f) uses the same mapping.
__global__ __launch_bounds__(256) void cvt(const void* __restrict__ x, const void* __restrict__ W_h,
                                           const void* __restrict__ adj,
                                           const void* a_h, const void* W_o, const void* a_o,
                                           const void* f1w, const void* f1b,
                                           const void* f2w, const void* f2b,
                                           u16* __restrict__ xc, u16* __restrict__ whc,
                                           float* a_hc, float* W_oc, float* a_oc,
                                           float* f1wc, float* f1bc, float* f2wc, float* f2bc,
                                           u64* __restrict__ bm) {
    const bool isb = adj_is_bf16(adj);
    const int b = blockIdx.x;
    if (b < CVT_BIG) {
        const int X4 = NN * NF / 4;                          // 640,000
        const int T4 = X4 + HEADS * NF * NH / 4;             // 705,536
        for (int i = b * 256 + threadIdx.x; i < T4; i += CVT_BIG * 256) {
            const void* src; u16* dst; int off;
            if (i < X4) { src = x; dst = xc; off = i; }
            else        { src = W_h; dst = whc; off = i - X4; }
            ushort4 o;
            if (isb) {
                o = ((const ushort4*)src)[off];              // already bf16: copy 8 B
            } else {
                u32x4 vv = ntload4(src, off);
                o.x = rne_bf16(__uint_as_float(vv[0])); o.y = rne_bf16(__uint_as_float(vv[1]));
                o.z = rne_bf16(__uint_as_float(vv[2])); o.w = rne_bf16(__uint_as_float(vv[3]));
            }
            ((ushort4*)dst)[off] = o;
        }
    } else if (b < CVT_BIG + 8) {
        const int s0 = HEADS * 2 * NH, s1 = HEADS * NH * NH, s2 = 2 * NH,
                  s3 = NH * 200, s4 = 200, s5 = 200 * NCLS, s6 = NCLS;
        const int total = s0 + s1 + s2 + s3 + s4 + s5 + s6;  // 54,960
        for (int i = (b - CVT_BIG) * 256 + threadIdx.x; i < total; i += 8 * 256) {
            const void* src; float* dst; int off = i;
            if (off < s0) { src = a_h; dst = a_hc; }
            else if ((off -= s0) < s1) { src = W_o;  dst = W_oc; }
            else if ((off -= s1) < s2) { src = a_o;  dst = a_oc; }
            else if ((off -= s2) < s3) { src = f1w;  dst = f1wc; }
            else if ((off -= s3) < s4) { src = f1b;  dst = f1bc; }
            else if ((off -= s4) < s5) { src = f2w;  dst = f2wc; }
            else { off -= s5;           src = f2b;  dst = f2bc; }
            dst[off] = isb ? up_bf16(((const u16*)src)[off]) : ((const float*)src)[off];
        }
    } else {
        // ---- adjacency -> bitmask: wave per row, NT streaming reads ----
        const int lane = threadIdx.x & 63;
        const int wid  = threadIdx.x >> 6;
        const int r = (b - CVT_BIG - 8) * 4 + wid;           // exact 5000
        u64* bmrow = bm + (size_t)r * BMW;
        if (!isb) {
            const float* row = (const float*)adj + (size_t)r * NN;     // 1250 u32x4 chunks
            #pragma unroll
            for (int pass = 0; pass < 2; ++pass) {
                u32x4 v[10];
                #pragma unroll
                for (int k = 0; k < 10; ++k) {
                    int c = (pass * 10 + k) * 64 + lane;
                    v[k] = (c < 1250) ? ntload4(row, c) : (u32x4){0u, 0u, 0u, 0u};
                }
                #pragma unroll
                for (int k = 0; k < 10; ++k) {
                    int i = pass * 10 + k;
                    #pragma unroll
                    for (int j = 0; j < 4; ++j) {
                        u64 m = __ballot(v[k][j] != 0u);
                        if (lane == j) bmrow[i * 4 + j] = m;
                    }
                }
            }
        } else {
            const u16* row = (const u16*)adj + (size_t)r * NN;         // 625 u32x4 chunks
            u32x4 v[10];
            #pragma unroll
            for (int k = 0; k < 10; ++k) {
                int c = k * 64 + lane;
                v[k] = (c < 625) ? ntload4(row, c) : (u32x4){0u, 0u, 0u, 0u};
            }
            #pragma unroll
            for (int k = 0; k < 10; ++k) {
                #pragma unroll
                for (int j = 0; j < 4; ++j) {
                    u64 mlo = __ballot((v[k][j] & 0xFFFFu) != 0u);
                    u64 mhi = __ballot((v[k][j] >> 16) != 0u);
                    if (lane == 2 * j)     bmrow[k * 8 + 2 * j]     = mlo;
                    if (lane == 2 * j + 1) bmrow[k * 8 + 2 * j + 1] = mhi;
                }
            }
        }
    }
}

// ---------------- K1: Wh = x @ W_h (bf16 MFMA) + fused f1/f2 epilogue ----------------
// C/D mapping row=(lane>>4)*4+r, col=lane&15 (R3 runtime probe: flag=1).
// Wh stored NODE-MAJOR [n][h*64+o]: one neighbor's 8 heads are contiguous 2 KB (R10).
__global__ __launch_bounds__(256) void gemm1_f(const bf16_t* __restrict__ x,
                                               const bf16_t* __restrict__ W_h,
                                               const float* __restrict__ a_h,
                                               float* __restrict__ Wh,
                                               float* __restrict__ f1,
                                               float* __restrict__ f2) {
    const int lane = threadIdx.x & 63;
    const int wid  = threadIdx.x >> 6;    // 16-col tile
    const int rg = blockIdx.x;            // 0..78 (79*64 = 5056 rows, guarded)
    const int h  = blockIdx.y;
    const int quad = lane >> 4;
    const int lr   = lane & 15;
    const int kq   = quad * 8;
    const int nCol = wid * 16 + lr;
    const bf16_t* Bh = W_h + (size_t)h * NF * NH;
    __shared__ float f1s[4][64], f2s[4][64];

    bf16x8 bfrag[16];
    #pragma unroll
    for (int s = 0; s < 16; ++s) {
        bf16x8 bb;
        #pragma unroll
        for (int j = 0; j < 8; ++j) bb[j] = Bh[(s * 32 + kq + j) * NH + nCol];
        bfrag[s] = bb;
    }
    const float a1c = a_h[h * 128 + nCol];
    const float a2c = a_h[h * 128 + NH + nCol];

    for (int t = 0; t < 4; ++t) {
        const int rb = rg * 64 + t * 16;
        int row  = rb + lr;
        int rowc = row < NN ? row : NN - 1;
        const bf16_t* xp = x + (size_t)rowc * NF + kq;
        f32x4 acc = {0.f, 0.f, 0.f, 0.f};
        #pragma unroll
        for (int s = 0; s < 16; ++s) {
            bf16x8 a = *(const bf16x8*)(xp + s * 32);
            acc = __builtin_amdgcn_mfma_f32_16x16x32_bf16(a, bfrag[s], acc, 0, 0, 0);
        }
        #pragma unroll
        for (int r = 0; r < 4; ++r) {
            int gr = rb + quad * 4 + r;
            if (gr < NN) Wh[(size_t)gr * (HEADS * NH) + h * NH + nCol] = acc[r];  // node-major
            float p1 = acc[r] * a1c, p2 = acc[r] * a2c;
            #pragma unroll
            for (int o = 8; o; o >>= 1) { p1 += __shfl_xor(p1, o); p2 += __shfl_xor(p2, o); }
            if (lr == 0) { f1s[wid][t * 16 + quad * 4 + r] = p1; f2s[wid][t * 16 + quad * 4 + r] = p2; }
        }
    }
    __syncthreads();
    if (wid == 0) {
        int gr = rg * 64 + lane;
        if (gr < NN) {
            f1[h * NN + gr] = f1s[0][lane] + f1s[1][lane] + f1s[2][lane] + f1s[3][lane];
            f2[h * NN + gr] = f2s[0][lane] + f2s[1][lane] + f2s[2][lane] + f2s[3][lane];
        }
    }
}

// ---------------- K2 agg1f: bitmask decode + ALL-heads layer-1 attention, block/node -------
// Decode (wave 0): 80 u64 words -> popc prefix-scan -> s_nbr. Gather: register/shfl
// dual-head loop (8 loads in flight/wave), Wh node-major.
__global__ __launch_bounds__(256) void agg1f(const void* __restrict__ adj,
                                             const u64* __restrict__ bm,
                                             const float* __restrict__ Wh,
                                             const float* __restrict__ f1,
                                             const float* __restrict__ f2,
                                             int* __restrict__ nbr, int* __restrict__ deg,
                                             float* __restrict__ h1) {
    const bool isb = adj_is_bf16(adj);
    const int lane = threadIdx.x & 63;
    const int wid  = threadIdx.x >> 6;
    const int n = blockIdx.x;               // 5000 blocks
    __shared__ int s_nbr[CAP];
    __shared__ int s_dall;

    if (wid == 0) {
        const u64* bmrow = bm + (size_t)n * BMW;
        int base = 0;
        #pragma unroll
        for (int r2 = 0; r2 < 2; ++r2) {
            int w = r2 * 64 + lane;
            u64 mw = (w < BMW) ? bmrow[w] : 0ull;
            int pc = __popcll(mw);
            int scan = pc;
            #pragma unroll
            for (int o = 1; o < 64; o <<= 1) {
                int t = __shfl_up(scan, o);
                if (lane >= o) scan += t;
            }
            int off = base + scan - pc;     // exclusive prefix
            while (mw) {
                int bb = __ffsll(mw) - 1;
                mw &= mw - 1;
                int elem;
                if (!isb) elem = ((w >> 2) * 64 + bb) * 4 + (w & 3);
                else      elem = ((w >> 3) * 64 + bb) * 8 + (w & 7);
                if (off < CAP) s_nbr[off] = elem;
                ++off;
            }
            base += __shfl(scan, 63);
        }
        if (lane == 0) s_dall = base < CAP ? base : CAP;
    }
    __syncthreads();
    const int dall = s_dall;
    for (int i = threadIdx.x; i < dall; i += 256) nbr[(size_t)n * CAP + i] = s_nbr[i];
    if (threadIdx.x == 0) deg[n] = dall;

    // ---- both heads (ha=wid, hb=wid+4) in registers; no LDS in hot loop ----
    const int ha = wid, hb = wid + 4;
    const int nb0 = (lane < dall) ? s_nbr[lane] : 0;
    const int nb1 = (lane + 64 < dall) ? s_nbr[lane + 64] : 0;
    const float f10 = f1[ha * NN + n], f11 = f1[hb * NN + n];
    const float* f2ha = f2 + (size_t)ha * NN;
    const float* f2hb = f2 + (size_t)hb * NN;

    float e00 = -INFINITY, e01 = -INFINITY, e10 = -INFINITY, e11 = -INFINITY;
    if (lane < dall) {
        float a = f10 + f2ha[nb0]; e00 = a > 0.f ? a : LRELU * a;
        float b = f11 + f2hb[nb0]; e10 = b > 0.f ? b : LRELU * b;
    }
    if (lane + 64 < dall) {
        float a = f10 + f2ha[nb1]; e01 = a > 0.f ? a : LRELU * a;
        float b = f11 + f2hb[nb1]; e11 = b > 0.f ? b : LRELU * b;
    }
    float mx0 = fmaxf(e00, e01), mx1 = fmaxf(e10, e11);
    #pragma unroll
    for (int o = 32; o; o >>= 1) {
        mx0 = fmaxf(mx0, __shfl_xor(mx0, o));
        mx1 = fmaxf(mx1, __shfl_xor(mx1, o));
    }
    float p00 = lane < dall ? expf(e00 - mx0) : 0.f;
    float p01 = lane + 64 < dall ? expf(e01 - mx0) : 0.f;
    float p10 = lane < dall ? expf(e10 - mx1) : 0.f;
    float p11 = lane + 64 < dall ? expf(e11 - mx1) : 0.f;
    float sm0 = p00 + p01, sm1 = p10 + p11;
    #pragma unroll
    for (int o = 32; o; o >>= 1) { sm0 += __shfl_xor(sm0, o); sm1 += __shfl_xor(sm1, o); }

    float A0 = 0.f, A1 = 0.f, A2 = 0.f, A3 = 0.f;
    float B0 = 0.f, B1 = 0.f, B2 = 0.f, B3 = 0.f;
    const float* W0 = Wh + ha * NH + lane;
    const float* W1 = Wh + hb * NH + lane;
    int j = 0;
    for (; j + 4 <= dall; j += 4) {
        #pragma unroll
        for (int i = 0; i < 4; ++i) {
            int jj = j + i;
            int sl = jj & 63;
            bool lo = jj < 64;                              // wave-uniform
            int   m  = lo ? __shfl(nb0, sl) : __shfl(nb1, sl);
            float a0 = lo ? __shfl(p00, sl) : __shfl(p01, sl);
            float a1 = lo ? __shfl(p10, sl) : __shfl(p11, sl);
            size_t base = (size_t)m * (HEADS * NH);
            float w0 = W0[base], w1 = W1[base];
            if (i == 0) { A0 += a0 * w0; B0 += a1 * w1; }
            else if (i == 1) { A1 += a0 * w0; B1 += a1 * w1; }
            else if (i == 2) { A2 += a0 * w0; B2 += a1 * w1; }
            else { A3 += a0 * w0; B3 += a1 * w1; }
        }
    }
    for (; j < dall; ++j) {
        int sl = j & 63;
        bool lo = j < 64;
        int   m  = lo ? __shfl(nb0, sl) : __shfl(nb1, sl);
        float a0 = lo ? __shfl(p00, sl) : __shfl(p01, sl);
        float a1 = lo ? __shfl(p10, sl) : __shfl(p11, sl);
        size_t base = (size_t)m * (HEADS * NH);
        A0 += a0 * W0[base]; B0 += a1 * W1[base];
    }
    float hv0 = (A0 + A1 + A2 + A3) / sm0;
    float hv1 = (B0 + B1 + B2 + B3) / sm1;
    hv0 = hv0 > 0.f ? hv0 : expf(hv0) - 1.f;                // ELU
    hv1 = hv1 > 0.f ? hv1 : expf(hv1) - 1.f;
    h1[(size_t)n * (HEADS * NH) + ha * NH + lane] = hv0;    // concat heads
    h1[(size_t)n * (HEADS * NH) + hb * NH + lane] = hv1;
}

// ---------------- K3: Wh2 = h1 @ W_o + g1/g2 — 4 nodes/block, W_o read once/block --------
__global__ __launch_bounds__(256) void gemm2_4(const float* __restrict__ h1,
                                               const float* __restrict__ W_o,
                                               const float* __restrict__ a_o,
                                               float* __restrict__ Wh2,
                                               float* __restrict__ g1,
                                               float* __restrict__ g2) {
    const int t = threadIdx.x;
    const int n0 = blockIdx.x * 4;          // exact 5000
    __shared__ float sh[4 * 512];           // 4 nodes' h1
    __shared__ float ps[4][4][64];          // (k-part, node, o)
    const float4* src = (const float4*)(h1 + (size_t)n0 * 512);
    ((float4*)sh)[t]       = src[t];
    ((float4*)sh)[t + 256] = src[t + 256];
    __syncthreads();
    const int o = t & 63, part = t >> 6;    // each thread: one o, one 128-wide k-slice, 4 nodes
    float a0 = 0.f, a1 = 0.f, a2 = 0.f, a3 = 0.f;
    const float* wo = W_o + part * 128 * 64 + o;
    const float* s0 = sh + part * 128;
    #pragma unroll 4
    for (int f = 0; f < 128; ++f) {
        float w = wo[f * 64];               // loaded once, used 4x
        a0 += s0[f] * w; a1 += s0[512 + f] * w; a2 += s0[1024 + f] * w; a3 += s0[1536 + f] * w;
    }
    ps[part][0][o] = a0; ps[part][1][o] = a1; ps[part][2][o] = a2; ps[part][3][o] = a3;
    __syncthreads();
    const int nd = t >> 6;                  // wave = node; lane = o
    float w2 = ps[0][nd][o] + ps[1][nd][o] + ps[2][nd][o] + ps[3][nd][o];
    Wh2[(size_t)(n0 + nd) * 64 + o] = w2;
    float p1 = w2 * a_o[o], p2 = w2 * a_o[64 + o];
    #pragma unroll
    for (int s = 32; s; s >>= 1) { p1 += __shfl_xor(p1, s); p2 += __shfl_xor(p2, s); }
    if (o == 0) { g1[n0 + nd] = p1; g2[n0 + nd] = p2; }
}

// ---------------- K4: layer-2 attention + aggregation + MLP head ----------------
__global__ __launch_bounds__(256) void agg2_mlp(const float* __restrict__ Wh2,
                                                const float* __restrict__ g1,
                                                const float* __restrict__ g2,
                                                const int* __restrict__ nbr,
                                                const int* __restrict__ deg,
                                                const float* __restrict__ fc1_w,
                                                const float* __restrict__ fc1_b,
                                                const float* __restrict__ fc2_w,
                                                const float* __restrict__ fc2_b,
                                                float* __restrict__ out) {
    const int lane = threadIdx.x & 63;
    const int wid  = threadIdx.x >> 6;
    const int t = threadIdx.x;
    const int n0 = blockIdx.x * 4;          // exact 5000
    const int n = n0 + wid;                 // gather phase: wave = node
    __shared__ float s_alpha[4][CAP];
    __shared__ int   s_nbr[4][CAP];
    __shared__ float s_h2[4][NH];
    __shared__ float s_h3[4][200];
    __shared__ float ps2[2][4][NCLS];
    const int d = deg[n];
    const int* nb = nbr + (size_t)n * CAP;
    const float gn = g1[n];

    float mx = -INFINITY;
    for (int j = lane; j < d; j += 64) {
        int m = nb[j];
        s_nbr[wid][j] = m;
        float e = gn + g2[m];
        e = e > 0.f ? e : LRELU * e;
        s_alpha[wid][j] = e;
        mx = fmaxf(mx, e);
    }
    #pragma unroll
    for (int o = 32; o; o >>= 1) mx = fmaxf(mx, __shfl_xor(mx, o));
    float sm = 0.f;
    for (int j = lane; j < d; j += 64) {
        float p = expf(s_alpha[wid][j] - mx);
        s_alpha[wid][j] = p;
        sm += p;
    }
    #pragma unroll
    for (int o = 32; o; o >>= 1) sm += __shfl_xor(sm, o);

    float acc0 = 0.f, acc1 = 0.f, acc2 = 0.f, acc3 = 0.f;
    int j = 0;
    for (; j + 4 <= d; j += 4) {
        acc0 += s_alpha[wid][j]     * Wh2[(size_t)s_nbr[wid][j]     * NH + lane];
        acc1 += s_alpha[wid][j + 1] * Wh2[(size_t)s_nbr[wid][j + 1] * NH + lane];
        acc2 += s_alpha[wid][j + 2] * Wh2[(size_t)s_nbr[wid][j + 2] * NH + lane];
        acc3 += s_alpha[wid][j + 3] * Wh2[(size_t)s_nbr[wid][j + 3] * NH + lane];
    }
    for (; j < d; ++j) acc0 += s_alpha[wid][j] * Wh2[(size_t)s_nbr[wid][j] * NH + lane];
    s_h2[wid][lane] = (acc0 + acc1 + acc2 + acc3) / sm;
    __syncthreads();

    // fc1: 200 threads x 4 nodes, fc1_w read once/block
    if (t < 200) {
        float b0 = 0.f, b1 = 0.f, b2 = 0.f, b3 = 0.f;
        #pragma unroll 4
        for (int f = 0; f < NH; ++f) {
            float w = fc1_w[f * 200 + t];
            b0 += s_h2[0][f] * w; b1 += s_h2[1][f] * w; b2 += s_h2[2][f] * w; b3 += s_h2[3][f] * w;
        }
        float bb = fc1_b[t];
        b0 += bb; b1 += bb; b2 += bb; b3 += bb;
        s_h3[0][t] = b0 > 0.f ? b0 : expf(b0) - 1.f;
        s_h3[1][t] = b1 > 0.f ? b1 : expf(b1) - 1.f;
        s_h3[2][t] = b2 > 0.f ? b2 : expf(b2) - 1.f;
        s_h3[3][t] = b3 > 0.f ? b3 : expf(b3) - 1.f;
    }
    __syncthreads();

    // fc2: 80 threads = (f-half, class) x 4 nodes; fc2_w read 2x/block
    if (t < 80) {
        const int o = t % 40, fh = t / 40;
        float c0 = 0.f, c1 = 0.f, c2 = 0.f, c3 = 0.f;
        #pragma unroll 4
        for (int f = fh * 100; f < fh * 100 + 100; ++f) {
            float w = fc2_w[f * NCLS + o];
            c0 += s_h3[0][f] * w; c1 += s_h3[1][f] * w; c2 += s_h3[2][f] * w; c3 += s_h3[3][f] * w;
        }
        ps2[fh][0][o] = c0; ps2[fh][1][o] = c1; ps2[fh][2][o] = c2; ps2[fh][3][o] = c3;
    }
    __syncthreads();
    if (t < 160) {
        const int nd = t / 40, o = t % 40;
        out[(size_t)(n0 + nd) * NCLS + o] = ps2[0][nd][o] + ps2[1][nd][o] + fc2_b[o];
    }
}

extern "C" void kernel_launch(void* const* d_in, const int* in_sizes, int n_in,
                              void* d_out, int out_size, void* d_ws, size_t ws_size,
                              hipStream_t stream) {
    const void* x     = d_in[0];
    const void* adj   = d_in[1];
    const void* W_h   = d_in[2];
    const void* a_h   = d_in[3];
    const void* W_o   = d_in[4];
    const void* a_o   = d_in[5];
    const void* fc1_w = d_in[6];
    const void* fc1_b = d_in[7];
    const void* fc2_w = d_in[8];
    const void* fc2_b = d_in[9];
    float* out = (float*)d_out;

    char* ws = (char*)d_ws;                         // all offsets 16B-aligned
    int*   nbr   = (int*)(ws + 0);                  //  2,560,000 B
    int*   deg   = (int*)(ws + 2560000);            //     20,000 B
    float* Wh    = (float*)(ws + 2580000);          // 10,240,000 B (node-major [n][512])
    float* f1    = (float*)(ws + 12820000);         //    160,000 B
    float* f2    = (float*)(ws + 12980000);         //    160,000 B
    float* h1    = (float*)(ws + 13140000);         // 10,240,000 B
    float* Wh2   = (float*)(ws + 23380000);         //  1,280,000 B
    float* g1    = (float*)(ws + 24660000);         //     20,000 B
    float* g2    = (float*)(ws + 24680000);         //     20,000 B
    u16*   xc    = (u16*)(ws + 24700000);           //  5,120,000 B
    u16*   whc   = (u16*)(ws + 29820000);           //    524,288 B
    float* a_hc  = (float*)(ws + 30344288);         //      4,096 B
    float* W_oc  = (float*)(ws + 30348384);         //    131,072 B
    float* a_oc  = (float*)(ws + 30479456);         //        512 B
    float* f1wc  = (float*)(ws + 30479968);         //     51,200 B
    float* f1bc  = (float*)(ws + 30531168);         //        800 B
    float* f2wc  = (float*)(ws + 30531968);         //     32,000 B
    float* f2bc  = (float*)(ws + 30563968);         //        160 B
    u64*   bm    = (u64*)(ws + 30564128);           //  3,200,000 B  (total ~33.8 MB)

    cvt<<<CVT_GRID, 256, 0, stream>>>(x, W_h, adj, a_h, W_o, a_o,
                                      fc1_w, fc1_b, fc2_w, fc2_b,
                                      xc, whc, a_hc, W_oc, a_oc,
                                      f1wc, f1bc, f2wc, f2bc, bm);
    gemm1_f<<<dim3(79, HEADS), 256, 0, stream>>>((const bf16_t*)xc, (const bf16_t*)whc,
                                                 a_hc, Wh, f1, f2);
    agg1f<<<NN, 256, 0, stream>>>(adj, bm, Wh, f1, f2, nbr, deg, h1);
    gemm2_4<<<NN / 4, 256, 0, stream>>>(h1, W_oc, a_oc, Wh2, g1, g2);
    agg2_mlp<<<NN / 4, 256, 0, stream>>>(Wh2, g1, g2, nbr, deg,
                                         f1wc, f1bc, f2wc, f2bc, out);
}